// Round 1
// baseline (3747.675 us; speedup 1.0000x reference)
//
#include <hip/hip_runtime.h>
#include <math.h>

#define TSTEPS 1000
#define NS 512
#define HD 512
#define MWG 16          // samples per workgroup
#define NWG 32          // workgroups
#define NWAVES 8
#define NTHREADS 512
#define APITCH 520      // a_lds row pitch in bf16 elements (+8 pad)

typedef __attribute__((ext_vector_type(8))) short bf16x8;
typedef __attribute__((ext_vector_type(4))) float f32x4;

__device__ __forceinline__ unsigned short f2bf(float f) {
    union { float f; unsigned u; } v; v.f = f;
    unsigned u = v.u + 0x7FFFu + ((v.u >> 16) & 1u);
    return (unsigned short)(u >> 16);
}

// relu(tanh(x)) via exp2+rcp (v_exp_f32 / v_rcp_f32, ~1ulp each)
__device__ __forceinline__ float relu_tanh(float x) {
    float xc = fminf(x, 10.0f);                                  // avoid exp overflow
    float e  = __builtin_amdgcn_exp2f(xc * 2.8853900817779268f); // e^(2x)
    float t  = (e - 1.0f) * __builtin_amdgcn_rcpf(e + 1.0f);
    return fmaxf(t, 0.0f);
}

// Pack W_rec f32 [k][n] (512x512) -> bf16 MFMA-B layout:
// Wp[nt*8192 + kb*512 + g*128 + c*8 + b] = W_rec[kb*32+g*8+b][nt*16+c]
__global__ void pack_wrec(const float* __restrict__ Wrec, unsigned short* __restrict__ Wp) {
    int tid = blockIdx.x * blockDim.x + threadIdx.x;
    if (tid >= 32768) return;
    int c  = tid & 15;
    int g  = (tid >> 4) & 3;
    int kb = (tid >> 6) & 15;
    int nt = tid >> 10;
    int k0 = kb * 32 + g * 8;
    int n  = nt * 16 + c;
    union { unsigned short s[8]; bf16x8 v; } buf;
#pragma unroll
    for (int b = 0; b < 8; ++b)
        buf.s[b] = f2bf(Wrec[(size_t)(k0 + b) * HD + n]);
    *(bf16x8*)(Wp + (size_t)tid * 8) = buf.v;
}

// Persistent per-sample-block RNN. KLDS = # of 32-wide k-blocks of W held in LDS (0 or 4).
template <int KLDS>
__global__ __launch_bounds__(NTHREADS)
void rnn_persist(const float* __restrict__ initdir,
                 const float* __restrict__ vel,
                 const float* __restrict__ fc_w,
                 const float* __restrict__ fc_b,
                 const float* __restrict__ W_in,
                 const float* __restrict__ W_out,
                 const float* __restrict__ bias,
                 const unsigned short* __restrict__ Wp,
                 float* __restrict__ out)
{
    extern __shared__ char smem[];
    unsigned short* a_lds = (unsigned short*)smem;                           // [16][APITCH] bf16
    float* outp = (float*)(smem + MWG * APITCH * 2);                         // [8][16][2] f32
    unsigned short* w_lds = (unsigned short*)(smem + MWG * APITCH * 2 + NWAVES * MWG * 2 * 4);

    const int tid  = threadIdx.x;
    const int lane = tid & 63;
    const int wv   = tid >> 6;        // wave 0..7, owns cols [wv*64, wv*64+64)
    const int g    = lane >> 4;       // 0..3
    const int c    = lane & 15;       // 0..15
    const int i0   = blockIdx.x * MWG;

    // Load resident part of W (k-blocks 0..KLDS-1, all 32 n-tiles) into LDS.
    if (KLDS == 4) {
        for (int idx = tid; idx < 8192; idx += NTHREADS) {   // 8192 chunks of 16B
            int r8 = idx & 63;
            int kb = (idx >> 6) & 3;
            int nt = idx >> 8;
            *(bf16x8*)(w_lds + ((nt * 4 + kb) * 512 + r8 * 8)) =
                *(const bf16x8*)(Wp + ((size_t)nt * 8192 + kb * 512 + r8 * 8));
        }
    }

    // Per-lane invariants for the 4 owned cols (one per n-tile) and 4 owned rows.
    float win0[4], win1[4], wo0[4], wo1[4], bc[4];
    float h[4][4];  // [j tile][r reg] ; D layout: row = g*4+r, col = wv*64+j*16+c
#pragma unroll
    for (int j = 0; j < 4; ++j) {
        int col = wv * 64 + j * 16 + c;
        win0[j] = W_in[col];
        win1[j] = W_in[HD + col];
        wo0[j]  = W_out[col * 2 + 0];
        wo1[j]  = W_out[col * 2 + 1];
        bc[j]   = bias[col];
        float fw0 = fc_w[col * 2 + 0], fw1 = fc_w[col * 2 + 1], fb = fc_b[col];
#pragma unroll
        for (int r = 0; r < 4; ++r) {
            int i = i0 + g * 4 + r;
            h[j][r] = initdir[i * 2 + 0] * fw0 + initdir[i * 2 + 1] * fw1 + fb;
        }
    }

    // Initial activation a(h0) -> LDS
#pragma unroll
    for (int j = 0; j < 4; ++j)
#pragma unroll
        for (int r = 0; r < 4; ++r)
            a_lds[(g * 4 + r) * APITCH + wv * 64 + j * 16 + c] = f2bf(relu_tanh(h[j][r]));
    __syncthreads();

    const unsigned short* abase = a_lds + c * APITCH + g * 8;  // A-frag: m=c, k=g*8+b
    const int lane_off = g * 128 + c * 8;                      // B-frag lane offset

    for (int t = 0; t < TSTEPS; ++t) {
        // velocities for this step (128 B per WG, L1-broadcast)
        float x0[4], x1[4];
#pragma unroll
        for (int r = 0; r < 4; ++r) {
            const float2 xv = *(const float2*)(vel + ((size_t)t * NS + i0 + g * 4 + r) * 2);
            x0[r] = xv.x; x1[r] = xv.y;
        }

        // acc = a_t @ W_rec for this wave's 4 n-tiles
        f32x4 acc[4];
        f32x4 z = {0.f, 0.f, 0.f, 0.f};
#pragma unroll
        for (int j = 0; j < 4; ++j) acc[j] = z;
#pragma unroll
        for (int kb = 0; kb < 16; ++kb) {
            bf16x8 af = *(const bf16x8*)(abase + kb * 32);
#pragma unroll
            for (int j = 0; j < 4; ++j) {
                bf16x8 bfr;
                if (KLDS == 4 && kb < 4)
                    bfr = *(const bf16x8*)(w_lds + ((wv * 4 + j) * 4 + kb) * 512 + lane_off);
                else
                    bfr = *(const bf16x8*)(Wp + (size_t)(wv * 4 + j) * 8192 + kb * 512 + lane_off);
                acc[j] = __builtin_amdgcn_mfma_f32_16x16x32_bf16(af, bfr, acc[j], 0, 0, 0);
            }
        }

        // h update (f32, regs), output partials (f32), next activation (bf16)
        float p0[4] = {0.f, 0.f, 0.f, 0.f}, p1[4] = {0.f, 0.f, 0.f, 0.f};
        unsigned short av[4][4];
#pragma unroll
        for (int j = 0; j < 4; ++j)
#pragma unroll
            for (int r = 0; r < 4; ++r) {
                float pre = acc[j][r] + x0[r] * win0[j] + x1[r] * win1[j] + bc[j];
                float hn  = 0.9f * h[j][r] + 0.1f * pre;
                h[j][r] = hn;
                p0[r] += hn * wo0[j];
                p1[r] += hn * wo1[j];
                av[j][r] = f2bf(relu_tanh(hn));
            }

        // reduce out-partials across the 16 lanes sharing g (cols)
#pragma unroll
        for (int m = 1; m <= 8; m <<= 1) {
#pragma unroll
            for (int r = 0; r < 4; ++r) {
                p0[r] += __shfl_xor(p0[r], m, 64);
                p1[r] += __shfl_xor(p1[r], m, 64);
            }
        }

        __syncthreads();   // all waves done reading a_t; outp from prev step consumed

#pragma unroll
        for (int j = 0; j < 4; ++j)
#pragma unroll
            for (int r = 0; r < 4; ++r)
                a_lds[(g * 4 + r) * APITCH + wv * 64 + j * 16 + c] = av[j][r];
        if (c == 0) {
#pragma unroll
            for (int r = 0; r < 4; ++r) {
                outp[wv * 32 + (g * 4 + r) * 2 + 0] = p0[r];
                outp[wv * 32 + (g * 4 + r) * 2 + 1] = p1[r];
            }
        }

        __syncthreads();   // a_{t+1} and outp ready

        if (tid < 32) {    // final cross-wave reduce + store (overlaps next MFMA phase)
            int row = tid >> 1, d = tid & 1;
            float s = 0.f;
#pragma unroll
            for (int ww = 0; ww < 8; ++ww) s += outp[ww * 32 + row * 2 + d];
            out[((size_t)t * NS + i0 + row) * 2 + d] = s;
        }
    }
}

extern "C" void kernel_launch(void* const* d_in, const int* in_sizes, int n_in,
                              void* d_out, int out_size, void* d_ws, size_t ws_size,
                              hipStream_t stream) {
    const float* initdir = (const float*)d_in[0];
    const float* vel     = (const float*)d_in[1];
    const float* fc_w    = (const float*)d_in[2];
    const float* fc_b    = (const float*)d_in[3];
    const float* W_in    = (const float*)d_in[4];
    const float* W_rec   = (const float*)d_in[5];
    const float* W_out   = (const float*)d_in[6];
    const float* bias    = (const float*)d_in[7];
    float* out           = (float*)d_out;
    unsigned short* Wp   = (unsigned short*)d_ws;   // 512 KB packed bf16 W_rec

    pack_wrec<<<64, 512, 0, stream>>>(W_rec, Wp);

    const int smem_big   = MWG * APITCH * 2 + NWAVES * MWG * 2 * 4 + 32 * 4 * 512 * 2; // 148736
    const int smem_small = MWG * APITCH * 2 + NWAVES * MWG * 2 * 4;                    // 17664

    hipError_t e = hipFuncSetAttribute(
        reinterpret_cast<const void*>(&rnn_persist<4>),
        hipFuncAttributeMaxDynamicSharedMemorySize, smem_big);

    if (e == hipSuccess) {
        rnn_persist<4><<<NWG, NTHREADS, smem_big, stream>>>(
            initdir, vel, fc_w, fc_b, W_in, W_out, bias, Wp, out);
    } else {
        rnn_persist<0><<<NWG, NTHREADS, smem_small, stream>>>(
            initdir, vel, fc_w, fc_b, W_in, W_out, bias, Wp, out);
    }
}

// Round 2
// 2677.193 us; speedup vs baseline: 1.3999x; 1.3999x over previous
//
#include <hip/hip_runtime.h>
#include <math.h>

#define TSTEPS 1000
#define NS 512
#define HD 512
#define MWG 16
#define NWG 32
#define NTHREADS 512
#define APITCH 520   // a_lds row pitch in bf16 elems (1040B: 16B-aligned, conflict-free b128 col reads)

typedef __attribute__((ext_vector_type(8))) short bf16x8;
typedef __attribute__((ext_vector_type(4))) float f32x4;

#define SMEM_BYTES (16*APITCH*2 + 3*512*4 + 8*16*2*4 + 32*4*512*2)  // 154880

__device__ __forceinline__ unsigned short f2bf(float f) {
    union { float f; unsigned u; } v; v.f = f;
    unsigned u = v.u + 0x7FFFu + ((v.u >> 16) & 1u);
    return (unsigned short)(u >> 16);
}

__device__ __forceinline__ unsigned pkbf(float lo, float hi) {
    unsigned r;
    asm("v_cvt_pk_bf16_f32 %0, %1, %2" : "=v"(r) : "v"(lo), "v"(hi));
    return r;
}

__device__ __forceinline__ float relu_tanh(float x) {
    float xc = fminf(x, 10.0f);
    float e  = __builtin_amdgcn_exp2f(xc * 2.8853900817779268f);
    float t  = (e - 1.0f) * __builtin_amdgcn_rcpf(e + 1.0f);
    return fmaxf(t, 0.0f);
}

// barrier that does NOT drain vmcnt (keeps global prefetches in flight)
__device__ __forceinline__ void barrier_lds() {
    asm volatile("s_waitcnt lgkmcnt(0)\n\ts_barrier" ::: "memory");
}

// k-permutation: orig col -> permuted k ; permuted k -> orig row
__device__ __forceinline__ int pi_col(int col) {
    return (col & ~63) | ((col & 15) << 2) | ((col >> 4) & 3);
}
__device__ __forceinline__ int pi_inv(int k) {
    return (k & ~63) | ((k & 3) << 4) | ((k >> 2) & 15);
}

// Pack W_rec (rows k-permuted) into MFMA-B fragment layout; tile 32 = W_rec@W_out; extras = W_in@W_out, bias@W_out.
__global__ void pack_wrec(const float* __restrict__ Wrec, const float* __restrict__ W_in,
                          const float* __restrict__ W_out, const float* __restrict__ bias,
                          unsigned short* __restrict__ Wp, float* __restrict__ extras) {
    if (blockIdx.x < 64) {
        int tid = blockIdx.x * 512 + threadIdx.x;     // 0..32767
        int c  = tid & 15;
        int g  = (tid >> 4) & 3;
        int kb = (tid >> 6) & 15;
        int nt = tid >> 10;
        int n  = nt * 16 + c;
        union { unsigned short s[8]; bf16x8 v; } buf;
#pragma unroll
        for (int b = 0; b < 8; ++b) {
            int k = kb * 32 + g * 8 + b;
            buf.s[b] = f2bf(Wrec[(size_t)pi_inv(k) * HD + n]);
        }
        *(bf16x8*)(Wp + (size_t)tid * 8) = buf.v;
    } else {
        __shared__ float wro[512][2];
        int tid = threadIdx.x;
        // Wro[k][d] = sum_h W_rec[k][h]*W_out[h][d]
        float s0 = 0.f, s1 = 0.f;
        for (int h = 0; h < HD; ++h) {
            float w = Wrec[(size_t)tid * HD + h];
            s0 += w * W_out[h * 2 + 0];
            s1 += w * W_out[h * 2 + 1];
        }
        wro[tid][0] = s0; wro[tid][1] = s1;
        __syncthreads();
        // pack tile 32 (cols 0,1 = Wro, rest zero)
        for (int i = tid; i < 1024; i += 512) {
            int c  = i & 15;
            int g  = (i >> 4) & 3;
            int kb = i >> 6;
            union { unsigned short s[8]; bf16x8 v; } buf;
#pragma unroll
            for (int b = 0; b < 8; ++b) {
                int k = kb * 32 + g * 8 + b;
                buf.s[b] = (c < 2) ? f2bf(wro[pi_inv(k)][c]) : (unsigned short)0;
            }
            *(bf16x8*)(Wp + (size_t)32 * 8192 + kb * 512 + (g * 16 + c) * 8) = buf.v;
        }
        // extras[0..3] = Wio[di][d] (di*2+d), extras[4..5] = bo[d]
        int lane = tid & 63, wv = tid >> 6;
        if (wv < 6) {
            float acc = 0.f;
#pragma unroll
            for (int m = 0; m < 8; ++m) {
                int h = lane + m * 64;
                float a = (wv < 4) ? W_in[(wv >> 1) * HD + h] : bias[h];
                acc += a * W_out[h * 2 + (wv & 1)];
            }
#pragma unroll
            for (int m = 32; m >= 1; m >>= 1) acc += __shfl_xor(acc, m, 64);
            if (lane == 0) extras[wv] = acc;
        }
    }
}

__global__ __launch_bounds__(NTHREADS, 2)
void rnn_persist(const float* __restrict__ initdir,
                 const float* __restrict__ vel,
                 const float* __restrict__ fc_w,
                 const float* __restrict__ fc_b,
                 const float* __restrict__ W_in,
                 const float* __restrict__ W_out,
                 const float* __restrict__ bias,
                 const unsigned short* __restrict__ Wp,
                 const float* __restrict__ extras,
                 float* __restrict__ out)
{
    extern __shared__ char smem[];
    unsigned short* a_lds  = (unsigned short*)smem;                          // [16][520] bf16
    float*          win_lds = (float*)(smem + 16 * APITCH * 2);              // [3][512] pi-ordered
    float*          opart   = win_lds + 3 * 512;                             // [8][16][2]
    unsigned short* w_lds   = (unsigned short*)((char*)(opart + 8 * 16 * 2));// [32*4][512] bf16

    const int tid  = threadIdx.x;
    const int lane = tid & 63;
    const int wv   = tid >> 6;
    const int g    = lane >> 4;
    const int c    = lane & 15;
    const int i0   = blockIdx.x * MWG;

    // ---- init: W kb0..3 into LDS (32 tiles x 4 kb x 1KB, lane-linear frags)
    for (int idx = tid; idx < 8192; idx += NTHREADS) {
        int inner = idx & 63;
        int b     = idx >> 6;            // nt*4+kb
        int nt = b >> 2, kb = b & 3;
        *(bf16x8*)(w_lds + b * 512 + inner * 8) =
            *(const bf16x8*)(Wp + (size_t)nt * 8192 + kb * 512 + inner * 8);
    }
    // ---- init: W_in / bias in pi-layout (float4-readable per lane)
    {
        int col = tid;
        int p = pi_col(col);
        win_lds[p]        = W_in[col];
        win_lds[512 + p]  = W_in[HD + col];
        win_lds[1024 + p] = bias[col];
    }
    // ---- init: persistent W fragments in VGPRs (kb 4..13, own 4 tiles)
    bf16x8 wreg[40];
#pragma unroll
    for (int kk = 0; kk < 10; ++kk)
#pragma unroll
        for (int j = 0; j < 4; ++j)
            wreg[kk * 4 + j] = *(const bf16x8*)(Wp + (size_t)(wv * 4 + j) * 8192 + (kk + 4) * 512 + lane * 8);
    bf16x8 wro[2];
#pragma unroll
    for (int s = 0; s < 2; ++s)
        wro[s] = *(const bf16x8*)(Wp + (size_t)32 * 8192 + (2 * wv + s) * 512 + lane * 8);

    // ---- init: h0 = fc(initdir); initial o-partials (h0 @ W_out) via shuffle
    float h[4][4];
    float p0[4] = {0.f, 0.f, 0.f, 0.f}, p1[4] = {0.f, 0.f, 0.f, 0.f};
#pragma unroll
    for (int j = 0; j < 4; ++j) {
        int col = wv * 64 + j * 16 + c;
        float fw0 = fc_w[col * 2], fw1 = fc_w[col * 2 + 1], fb = fc_b[col];
        float wo0 = W_out[col * 2], wo1 = W_out[col * 2 + 1];
#pragma unroll
        for (int r = 0; r < 4; ++r) {
            int i = i0 + g * 4 + r;
            float hv = initdir[i * 2] * fw0 + initdir[i * 2 + 1] * fw1 + fb;
            h[j][r] = hv;
            p0[r] += hv * wo0;
            p1[r] += hv * wo1;
        }
    }
    unsigned short* awr = a_lds + wv * 64 + 4 * c;
#pragma unroll
    for (int r = 0; r < 4; ++r) {
        uint2 v;
        v.x = pkbf(relu_tanh(h[0][r]), relu_tanh(h[1][r]));
        v.y = pkbf(relu_tanh(h[2][r]), relu_tanh(h[3][r]));
        *(uint2*)(awr + (g * 4 + r) * APITCH) = v;
    }
#pragma unroll
    for (int m = 1; m <= 8; m <<= 1)
#pragma unroll
        for (int r = 0; r < 4; ++r) {
            p0[r] += __shfl_xor(p0[r], m, 64);
            p1[r] += __shfl_xor(p1[r], m, 64);
        }
    if (c == 0) {
#pragma unroll
        for (int r = 0; r < 4; ++r) {
            opart[wv * 32 + (g * 4 + r) * 2 + 0] = p0[r];
            opart[wv * 32 + (g * 4 + r) * 2 + 1] = p1[r];
        }
    }

    // ---- x prefetch for t=0
    f32x4 xa = *(const f32x4*)(vel + (size_t)(i0 + 4 * g) * 2);
    f32x4 xb = *(const f32x4*)(vel + (size_t)(i0 + 4 * g) * 2 + 4);

    __syncthreads();

    // ---- reducer state (tid<32): o_0 = h0 @ W_out
    const int rrow = tid >> 1, rd = tid & 1;
    float o_state = 0.f, wio_x = 0.f, wio_y = 0.f, bo_d = 0.f;
    if (tid < 32) {
        float s = 0.f;
#pragma unroll
        for (int w = 0; w < 8; ++w) s += opart[w * 32 + rrow * 2 + rd];
        o_state = s;
        wio_x = extras[rd];
        wio_y = extras[2 + rd];
        bo_d  = extras[4 + rd];
    }

    const unsigned short* abase = a_lds + c * APITCH + g * 8;

#pragma unroll 1
    for (int t = 0; t < TSTEPS; ++t) {
        // ---- finish step t-1's output (overlaps MFMA phase of other waves)
        if (t > 0 && tid < 32) {
            float s = 0.f;
#pragma unroll
            for (int w = 0; w < 8; ++w) s += opart[w * 32 + rrow * 2 + rd];
            const float2 xv = *(const float2*)(vel + ((size_t)(t - 1) * NS + i0 + rrow) * 2);
            o_state = 0.9f * o_state + 0.1f * (s + xv.x * wio_x + xv.y * wio_y + bo_d);
            out[((size_t)(t - 1) * NS + i0 + rrow) * 2 + rd] = o_state;
        }

        // ---- streamed W (kb 14,15): issue early, consume at loop end
        bf16x8 st0[4], st1[4];
#pragma unroll
        for (int j = 0; j < 4; ++j)
            st0[j] = *(const bf16x8*)(Wp + (size_t)(wv * 4 + j) * 8192 + 14 * 512 + lane * 8);

        f32x4 z = {0.f, 0.f, 0.f, 0.f};
        f32x4 acc[4];
#pragma unroll
        for (int j = 0; j < 4; ++j) acc[j] = z;

#pragma unroll
        for (int kb = 0; kb < 16; ++kb) {
            if (kb == 9) {
#pragma unroll
                for (int j = 0; j < 4; ++j)
                    st1[j] = *(const bf16x8*)(Wp + (size_t)(wv * 4 + j) * 8192 + 15 * 512 + lane * 8);
            }
            bf16x8 af = *(const bf16x8*)(abase + kb * 32);
#pragma unroll
            for (int j = 0; j < 4; ++j) {
                bf16x8 bfr;
                if (kb < 4)       bfr = *(const bf16x8*)(w_lds + ((wv * 4 + j) * 4 + kb) * 512 + lane * 8);
                else if (kb < 14) bfr = wreg[(kb - 4) * 4 + j];
                else if (kb == 14) bfr = st0[j];
                else              bfr = st1[j];
                acc[j] = __builtin_amdgcn_mfma_f32_16x16x32_bf16(af, bfr, acc[j], 0, 0, 0);
            }
        }

        // ---- o-partials: this wave's 2 k-blocks against Wro
        f32x4 acco = z;
#pragma unroll
        for (int s = 0; s < 2; ++s) {
            bf16x8 af = *(const bf16x8*)(abase + (2 * wv + s) * 32);
            acco = __builtin_amdgcn_mfma_f32_16x16x32_bf16(af, wro[s], acco, 0, 0, 0);
        }

        // ---- h update + next activation (packed bf16 pairs)
        const f32x4 w0v = *(const f32x4*)(win_lds + wv * 64 + 4 * c);
        const f32x4 w1v = *(const f32x4*)(win_lds + 512 + wv * 64 + 4 * c);
        const f32x4 bcv = *(const f32x4*)(win_lds + 1024 + wv * 64 + 4 * c);
        float x0[4] = {xa[0], xa[2], xb[0], xb[2]};
        float x1[4] = {xa[1], xa[3], xb[1], xb[3]};
        uint2 wval[4];
#pragma unroll
        for (int r = 0; r < 4; ++r) {
            float av[4];
#pragma unroll
            for (int j = 0; j < 4; ++j) {
                float pre = acc[j][r] + x0[r] * w0v[j] + x1[r] * w1v[j] + bcv[j];
                float hn  = 0.9f * h[j][r] + 0.1f * pre;
                h[j][r] = hn;
                av[j] = relu_tanh(hn);
            }
            wval[r].x = pkbf(av[0], av[1]);
            wval[r].y = pkbf(av[2], av[3]);
        }

        // ---- prefetch x for t+1 (stays in flight across barriers; vmcnt not drained)
        {
            int tn = (t + 1 < TSTEPS) ? (t + 1) : t;
            xa = *(const f32x4*)(vel + ((size_t)tn * NS + i0 + 4 * g) * 2);
            xb = *(const f32x4*)(vel + ((size_t)tn * NS + i0 + 4 * g) * 2 + 4);
        }

        barrier_lds();   // all reads of a_t done

#pragma unroll
        for (int r = 0; r < 4; ++r)
            *(uint2*)(awr + (g * 4 + r) * APITCH) = wval[r];
        if (c < 2) {
#pragma unroll
            for (int r = 0; r < 4; ++r)
                opart[wv * 32 + (g * 4 + r) * 2 + c] = acco[r];
        }

        barrier_lds();   // a_{t+1} + o-partials visible
    }

    // ---- epilogue: out[999]
    if (tid < 32) {
        float s = 0.f;
#pragma unroll
        for (int w = 0; w < 8; ++w) s += opart[w * 32 + rrow * 2 + rd];
        const float2 xv = *(const float2*)(vel + ((size_t)(TSTEPS - 1) * NS + i0 + rrow) * 2);
        o_state = 0.9f * o_state + 0.1f * (s + xv.x * wio_x + xv.y * wio_y + bo_d);
        out[((size_t)(TSTEPS - 1) * NS + i0 + rrow) * 2 + rd] = o_state;
    }
}

extern "C" void kernel_launch(void* const* d_in, const int* in_sizes, int n_in,
                              void* d_out, int out_size, void* d_ws, size_t ws_size,
                              hipStream_t stream) {
    (void)in_sizes; (void)n_in; (void)out_size; (void)ws_size;
    const float* initdir = (const float*)d_in[0];
    const float* vel     = (const float*)d_in[1];
    const float* fc_w    = (const float*)d_in[2];
    const float* fc_b    = (const float*)d_in[3];
    const float* W_in    = (const float*)d_in[4];
    const float* W_rec   = (const float*)d_in[5];
    const float* W_out   = (const float*)d_in[6];
    const float* bias    = (const float*)d_in[7];
    float* out           = (float*)d_out;

    unsigned short* Wp = (unsigned short*)d_ws;                    // 33 tiles * 16KB = 528KB
    float* extras      = (float*)((char*)d_ws + (size_t)33 * 8192 * 2);  // Wio[4], bo[2]

    pack_wrec<<<65, 512, 0, stream>>>(W_rec, W_in, W_out, bias, Wp, extras);

    hipFuncSetAttribute(reinterpret_cast<const void*>(&rnn_persist),
                        hipFuncAttributeMaxDynamicSharedMemorySize, SMEM_BYTES);

    rnn_persist<<<NWG, NTHREADS, SMEM_BYTES, stream>>>(
        initdir, vel, fc_w, fc_b, W_in, W_out, bias, Wp, extras, out);
}